// Round 12
// baseline (251.704 us; speedup 1.0000x reference)
//
#include <hip/hip_runtime.h>
#include <stdint.h>
#include <stddef.h>

// MixedScaleAttention round 12: r10-green body VERBATIM (158.5us), single
// change: __launch_bounds__(512,4) -> (512,5). 102-reg cap targets 5 waves/SIMD
// = 20 waves/CU (+25% occupancy). r11's 3-change bundle regressed (register
// growth in attn) and is fully reverted. If this spills (WRITE_SIZE up,
// dur >= 158), r10 is the keeper.

#define B_ 2048
#define E_ 128
#define L2E 1.44269504088896f

typedef __attribute__((ext_vector_type(8))) short bf8;
typedef __attribute__((ext_vector_type(16))) float f16f;
typedef __attribute__((ext_vector_type(2))) int iv2;

#define ZERO16 ((f16f){0.f,0.f,0.f,0.f,0.f,0.f,0.f,0.f,0.f,0.f,0.f,0.f,0.f,0.f,0.f,0.f})

__device__ __forceinline__ unsigned int cvtpk(float lo, float hi) {
  unsigned int r;
  asm("v_cvt_pk_bf16_f32 %0, %1, %2" : "=v"(r) : "v"(lo), "v"(hi));
  return r;
}

__device__ __forceinline__ unsigned short f2bf(float f) {
  return (unsigned short)cvtpk(f, f);  // single instruction, RNE
}

__device__ __forceinline__ float fexp2(float x) {
#if __has_builtin(__builtin_amdgcn_exp2f)
  return __builtin_amdgcn_exp2f(x);
#else
  return exp2f(x);
#endif
}

union FR { unsigned long long q[2]; unsigned int u[4]; bf8 v; };

// 8B-granular XOR swizzle: byte col ^ ((row&15)<<3). All reads are 2x b64.
__device__ __forceinline__ bf8 lds_frag(const unsigned char* t, int row, int stride, int colb) {
  FR f;
  const unsigned char* base = t + row * stride;
  const int x = (row & 15) << 3;
  f.q[0] = *(const unsigned long long*)(base + (colb ^ x));
  f.q[1] = *(const unsigned long long*)(base + ((colb + 8) ^ x));
  return f.v;
}

__device__ __forceinline__ void lds_w16(unsigned char* t, int row, int stride, int colb, unsigned short v) {
  *(unsigned short*)(t + row * stride + (colb ^ ((row & 15) << 3))) = v;
}

__device__ __forceinline__ void lds_w32(unsigned char* t, int row, int stride, int colb, unsigned int v) {
  *(unsigned int*)(t + row * stride + (colb ^ ((row & 15) << 3))) = v;  // colb 4-aligned
}

__device__ __forceinline__ bf8 gfrag(const float* p) {
  float4 a = *(const float4*)p;
  float4 b = *(const float4*)(p + 4);
  FR f;
  f.u[0] = cvtpk(a.x, a.y);
  f.u[1] = cvtpk(a.z, a.w);
  f.u[2] = cvtpk(b.x, b.y);
  f.u[3] = cvtpk(b.z, b.w);
  return f.v;
}

struct P2 {
  const float* query;
  const float* keys;
  const int* km;
  const float* rpb[3];  // original layout [h][64 q][128 key]
  const unsigned short* wqP[3];
  const unsigned short* wkvP[3];
  const unsigned short* wpP[3];
  const float* bq[3];
  const float* bkv[3];
  const float* bp[3];
  float* out;
};

template <int SD>
__device__ __forceinline__ void do_kv_job(const P2& p, int b, int grow_base, int klocal_base,
                                          int colbase, const unsigned short* wkvP, const float* bkv,
                                          unsigned char* Kst, unsigned char* Vt,
                                          int kdim_base, int vdim_base, int nt0, int nt1, int lane) {
  constexpr int KT = SD / 16;
  const int l31 = lane & 31, hi = lane >> 5;
  bf8 afr[KT];
  const float* ap = p.keys + ((size_t)(grow_base + l31) * B_ + b) * E_ + colbase + hi * 8;
#pragma unroll
  for (int kk = 0; kk < KT; ++kk) afr[kk] = gfrag(ap + kk * 16);
  for (int nt = nt0; nt < nt1; ++nt) {
    f16f acc = ZERO16;
#pragma unroll
    for (int kk = 0; kk < KT; ++kk) {
      bf8 w = *(const bf8*)(wkvP + (((size_t)(nt * KT + kk)) * 64 + lane) * 8);
      acc = __builtin_amdgcn_mfma_f32_32x32x16_bf16(afr[kk], w, acc, 0, 0, 0);
    }
    int n = nt * 32 + l31;
    float bias = bkv[n];
    if (nt * 32 < SD) {  // K half (uniform per nt)
      int col = (kdim_base + n) * 2;
#pragma unroll
      for (int r = 0; r < 16; ++r) {
        int row = klocal_base + (r & 3) + 8 * (r >> 2) + 4 * hi;
        lds_w16(Kst, row, 128, col, f2bf(acc[r] + bias));
      }
    } else {             // V half -> transposed Vt[d][key]; consecutive keys pair
      int d = vdim_base + n - SD;
#pragma unroll
      for (int t2 = 0; t2 < 8; ++t2) {
        int r0 = 2 * t2;
        int key0 = klocal_base + (r0 & 3) + 8 * (r0 >> 2) + 4 * hi;  // even
        lds_w32(Vt, d, 256, key0 * 2, cvtpk(acc[r0] + bias, acc[r0 + 1] + bias));
      }
    }
  }
}

template <int SD>
__device__ __forceinline__ void do_q_job(const P2& p, int b, int qt, int colbase,
                                         const unsigned short* wqP, const float* bq,
                                         unsigned char* Qst, int qdim_base, int nt0, int nt1, int lane) {
  constexpr int KT = SD / 16;
  const int l31 = lane & 31, hi = lane >> 5;
  bf8 afr[KT];
  const float* ap = p.query + ((size_t)(qt * 32 + l31) * B_ + b) * E_ + colbase + hi * 8;
#pragma unroll
  for (int kk = 0; kk < KT; ++kk) afr[kk] = gfrag(ap + kk * 16);
  for (int nt = nt0; nt < nt1; ++nt) {
    f16f acc = ZERO16;
#pragma unroll
    for (int kk = 0; kk < KT; ++kk) {
      bf8 w = *(const bf8*)(wqP + (((size_t)(nt * KT + kk)) * 64 + lane) * 8);
      acc = __builtin_amdgcn_mfma_f32_32x32x16_bf16(afr[kk], w, acc, 0, 0, 0);
    }
    int n = nt * 32 + l31;
    float bias = bq[n];
    int col = (qdim_base + n) * 2;
#pragma unroll
    for (int r = 0; r < 16; ++r) {
      int row = qt * 32 + (r & 3) + 8 * (r >> 2) + 4 * hi;
      // fold softmax scale (1/4) and log2e into Q
      lds_w16(Qst, row, 128, col, f2bf((acc[r] + bias) * (0.25f * L2E)));
    }
  }
}

template <int SD>
__device__ __forceinline__ void do_out_job(const P2& p, const unsigned char* Xst, int xdim_base,
                                           int qt, int nt, const unsigned short* wpP, const float* bp,
                                           int b, int colbase, int lane) {
  constexpr int KT = SD / 16;
  const int l31 = lane & 31, hi = lane >> 5;
  f16f acc = ZERO16;
#pragma unroll
  for (int kk = 0; kk < KT; ++kk) {
    bf8 a = lds_frag(Xst, qt * 32 + l31, 128, (xdim_base + kk * 16 + hi * 8) * 2);
    bf8 w = *(const bf8*)(wpP + (((size_t)(nt * KT + kk)) * 64 + lane) * 8);
    acc = __builtin_amdgcn_mfma_f32_32x32x16_bf16(a, w, acc, 0, 0, 0);
  }
  int c = colbase + nt * 32 + l31;
  float bias = bp[nt * 32 + l31];
#pragma unroll
  for (int r = 0; r < 16; ++r) {
    int q = qt * 32 + (r & 3) + 8 * (r >> 2) + 4 * hi;
    p.out[((size_t)q * B_ + b) * E_ + c] = acc[r] + bias;  // 128B-contiguous per 32 lanes
  }
}

// (group,head,qt) attention: FROZEN r7-green dataflow. Swapped QK^T ->
// fixed-shift exp2 (no max pass) -> in-register normalize (f32, before cvt_pk,
// before permlane) -> permlane -> PV -> plain Xst write.
__device__ __forceinline__ void do_attn_job(const P2& p, const unsigned char* Kst,
                                            const unsigned char* Qst, const unsigned char* Vt,
                                            unsigned char* Xst, const float* kmf,
                                            int dimcol, int km_base, const float* rpb_orig,
                                            int qt, int lane) {
  const int l31 = lane & 31, hi = lane >> 5;
  f16f s[4];
#pragma unroll
  for (int kt = 0; kt < 4; ++kt) {
    bf8 kf = lds_frag(Kst, kt * 32 + l31, 128, (dimcol + hi * 8) * 2);
    bf8 qf = lds_frag(Qst, qt * 32 + l31, 128, (dimcol + hi * 8) * 2);
    f16f z = ZERO16;
    s[kt] = __builtin_amdgcn_mfma_f32_32x32x16_bf16(kf, qf, z, 0, 0, 0);  // S^T[key][q]
  }
  // + rpb + mask bias (pre-scaled by log2e; mask carries -8 shift)
  {
    const float* ro = rpb_orig + (qt * 32 + l31) * 128;
#pragma unroll
    for (int kt = 0; kt < 4; ++kt)
#pragma unroll
      for (int r = 0; r < 16; ++r) {
        int krow = kt * 32 + (r & 3) + 8 * (r >> 2) + 4 * hi;
        s[kt][r] = fmaf(ro[krow], L2E, s[kt][r] + kmf[km_base + krow]);
      }
  }
  // fixed-shift softmax: no max pass; exponents bounded by construction
  float sum = 0.f;
#pragma unroll
  for (int kt = 0; kt < 4; ++kt)
#pragma unroll
    for (int r = 0; r < 16; ++r) {
      float e = fexp2(s[kt][r]);
      s[kt][r] = e;
      sum += e;
    }
  sum += __shfl_xor(sum, 32);
  const float inv = 1.0f / sum;

  // pack normalized P to bf16 and redistribute into PV A-frags; PV accumulate
  f16f o = ZERO16;
  const int vrow = dimcol + (l31 & 15);
#pragma unroll
  for (int kt = 0; kt < 4; ++kt) {
    unsigned int pk[8];
#pragma unroll
    for (int j = 0; j < 8; ++j) pk[j] = cvtpk(s[kt][2 * j] * inv, s[kt][2 * j + 1] * inv);
#pragma unroll
    for (int tt = 0; tt < 2; ++tt) {
      FR af;
#if __has_builtin(__builtin_amdgcn_permlane32_swap)
      iv2 w02 = __builtin_amdgcn_permlane32_swap((int)pk[4 * tt], (int)pk[4 * tt + 2], false, false);
      iv2 w13 = __builtin_amdgcn_permlane32_swap((int)pk[4 * tt + 1], (int)pk[4 * tt + 3], false, false);
      af.u[0] = (unsigned)w02[0]; af.u[1] = (unsigned)w13[0];
      af.u[2] = (unsigned)w02[1]; af.u[3] = (unsigned)w13[1];
#else
      unsigned a0 = pk[4 * tt], a1 = pk[4 * tt + 1], b0 = pk[4 * tt + 2], b1 = pk[4 * tt + 3];
      unsigned pa0 = (unsigned)__shfl_xor((int)a0, 32);
      unsigned pa1 = (unsigned)__shfl_xor((int)a1, 32);
      unsigned pb0 = (unsigned)__shfl_xor((int)b0, 32);
      unsigned pb1 = (unsigned)__shfl_xor((int)b1, 32);
      af.u[0] = hi ? pb0 : a0; af.u[1] = hi ? pb1 : a1;
      af.u[2] = hi ? b0 : pa0; af.u[3] = hi ? b1 : pa1;
#endif
      int t = kt * 2 + tt;
      bf8 vf = lds_frag(Vt, vrow, 256, (t * 16 + hi * 8) * 2);
      o = __builtin_amdgcn_mfma_f32_32x32x16_bf16(af.v, vf, o, 0, 0, 0);  // X[q][d]
    }
  }
  if (l31 < 16) {
#pragma unroll
    for (int r = 0; r < 16; ++r) {
      int q = qt * 32 + (r & 3) + 8 * (r >> 2) + 4 * hi;
      lds_w16(Xst, q, 128, (dimcol + l31) * 2, f2bf(o[r]));
    }
  }
}

__launch_bounds__(512, 5)
__global__ void msa12(P2 p) {
  __shared__ __align__(16) unsigned char Qst[8192];    // [64 q][64 dim] bf16
  __shared__ __align__(16) unsigned char Kst[16384];   // [128 key][64 dim] bf16
  __shared__ __align__(16) unsigned char Vt[16384];    // [64 d][128 key] bf16
  __shared__ __align__(16) unsigned char Xst[8192];    // [64 q][64 dim] bf16
  __shared__ float kmf[256];                           // (mask bias - 8) * log2e
  const int bid = blockIdx.x;
  const int b = bid >> 1;
  const int role = bid & 1;
  const int tid = threadIdx.x;
  const int wave = tid >> 6;
  const int lane = tid & 63;

  if (role == 0) {
    // ======== groups 0,1: proj -> attn -> out (3 phases) ========
    if (tid < 256) kmf[tid] = (p.km[(size_t)b * 384 + tid] ? -108.0f : -8.0f) * L2E;
    {
      int g = wave >> 2, mt = wave & 3;
      do_kv_job<32>(p, b, g * 128 + mt * 32, mt * 32, g * 32, p.wkvP[g], p.bkv[g],
                    Kst, Vt, g * 32, g * 32, 0, 2, lane);
      if (wave < 4) {
        int qg = wave >> 1, qt = wave & 1;
        do_q_job<32>(p, b, qt, qg * 32, p.wqP[qg], p.bq[qg], Qst, qg * 32, 0, 1, lane);
      }
    }
    __syncthreads();
    {
      int g = wave >> 2, head = (wave >> 1) & 1, qt = wave & 1;
      do_attn_job(p, Kst, Qst, Vt, Xst, kmf, g * 32 + head * 16, g * 128,
                  p.rpb[g] + head * 8192, qt, lane);
    }
    __syncthreads();
    if (wave < 4) {
      int g = wave >> 1, qt = wave & 1;
      do_out_job<32>(p, Xst, g * 32, qt, 0, p.wpP[g], p.bp[g], b, g * 32, lane);
    }
  } else {
    // ======== group 2: proj -> attn -> out (3 phases) ========
    if (tid < 128) kmf[tid] = (p.km[(size_t)b * 384 + 256 + tid] ? -108.0f : -8.0f) * L2E;
    {
      int mt = wave >> 1, nth = wave & 1;
      do_kv_job<64>(p, b, 256 + mt * 32, mt * 32, 64, p.wkvP[2], p.bkv[2],
                    Kst, Vt, 0, 0, nth * 2, nth * 2 + 2, lane);
      if (wave < 4) {
        int qt = wave >> 1, nt = wave & 1;
        do_q_job<64>(p, b, qt, 64, p.wqP[2], p.bq[2], Qst, 0, nt, nt + 1, lane);
      }
    }
    __syncthreads();
    {
      int head = wave >> 1, qt = wave & 1;
      do_attn_job(p, Kst, Qst, Vt, Xst, kmf, head * 16, 0,
                  p.rpb[2] + head * 8192, qt, lane);
    }
    __syncthreads();
    if (wave < 4) {
      int qt = wave >> 1, nt = wave & 1;
      do_out_job<64>(p, Xst, 0, qt, nt, p.wpP[2], p.bp[2], b, 64, lane);
    }
  }
}

// ---- pre-kernel: pack weights to MFMA B-frag order (bf16) ----
struct PrepP {
  const float* wsrc[9];
  unsigned short* wdst;
};

__global__ void prep(PrepP pp) {
  int i = blockIdx.x * 256 + threadIdx.x;
  if (i < 24576) {
    const int off[10] = {0, 1024, 3072, 4096, 5120, 7168, 8192, 12288, 20480, 24576};
    const int SDs[9] = {32, 32, 32, 32, 32, 32, 64, 64, 64};
    int r = 0;
    while (i >= off[r + 1]) ++r;
    int e = i - off[r];
    int j = e & 7, lane = (e >> 3) & 63, blk = e >> 9;
    int KT = SDs[r] >> 4;
    int nt = blk / KT, kk = blk - nt * KT;
    int row = nt * 32 + (lane & 31);
    int col = kk * 16 + (lane >> 5) * 8 + j;
    pp.wdst[i] = f2bf(pp.wsrc[r][row * SDs[r] + col]);
  }
}

extern "C" void kernel_launch(void* const* d_in, const int* in_sizes, int n_in,
                              void* d_out, int out_size, void* d_ws, size_t ws_size,
                              hipStream_t stream) {
  (void)in_sizes; (void)n_in; (void)out_size; (void)ws_size;
  P2 p;
  PrepP pp;
  p.query = (const float*)d_in[0];
  p.keys = (const float*)d_in[1];
  p.km = (const int*)d_in[2];
  const int base[3] = {3, 10, 17};
  unsigned short* wbf = (unsigned short*)d_ws;
  const int woff[9] = {0, 1024, 3072, 4096, 5120, 7168, 8192, 12288, 20480};
  for (int g = 0; g < 3; ++g) {
    p.rpb[g] = (const float*)d_in[base[g]];
    p.bq[g] = (const float*)d_in[base[g] + 2];
    p.bkv[g] = (const float*)d_in[base[g] + 4];
    p.bp[g] = (const float*)d_in[base[g] + 6];
    p.wqP[g] = wbf + woff[g * 3];
    p.wkvP[g] = wbf + woff[g * 3 + 1];
    p.wpP[g] = wbf + woff[g * 3 + 2];
    pp.wsrc[g * 3] = (const float*)d_in[base[g] + 1];
    pp.wsrc[g * 3 + 1] = (const float*)d_in[base[g] + 3];
    pp.wsrc[g * 3 + 2] = (const float*)d_in[base[g] + 5];
  }
  p.out = (float*)d_out;
  pp.wdst = wbf;

  prep<<<96, 256, 0, stream>>>(pp);
  msa12<<<4096, 512, 0, stream>>>(p);
}

// Round 13
// 156.346 us; speedup vs baseline: 1.6099x; 1.6099x over previous
//
#include <hip/hip_runtime.h>
#include <stdint.h>
#include <stddef.h>

// MixedScaleAttention round 13: r10-green (158.5us) + two reg-light chain cuts:
//  1) phase-1 q-job A-fragment loads hoisted BEFORE the kv job for waves that
//     run both (hides ~500-900cy global latency on the phase-1 critical path)
//  2) softmax sum as 4 per-kt partials + tree combine (cuts 64-deep add chain)
// Everything else identical to r10. (512,4); attn dataflow FROZEN at r7/r10.
// Occupancy ladder mapped: (512,4)=158 / (512,5)=252 spill / (512,6)=637 spill.

#define B_ 2048
#define E_ 128
#define L2E 1.44269504088896f

typedef __attribute__((ext_vector_type(8))) short bf8;
typedef __attribute__((ext_vector_type(16))) float f16f;
typedef __attribute__((ext_vector_type(2))) int iv2;

#define ZERO16 ((f16f){0.f,0.f,0.f,0.f,0.f,0.f,0.f,0.f,0.f,0.f,0.f,0.f,0.f,0.f,0.f,0.f})

__device__ __forceinline__ unsigned int cvtpk(float lo, float hi) {
  unsigned int r;
  asm("v_cvt_pk_bf16_f32 %0, %1, %2" : "=v"(r) : "v"(lo), "v"(hi));
  return r;
}

__device__ __forceinline__ unsigned short f2bf(float f) {
  return (unsigned short)cvtpk(f, f);  // single instruction, RNE
}

__device__ __forceinline__ float fexp2(float x) {
#if __has_builtin(__builtin_amdgcn_exp2f)
  return __builtin_amdgcn_exp2f(x);
#else
  return exp2f(x);
#endif
}

union FR { unsigned long long q[2]; unsigned int u[4]; bf8 v; };

// 8B-granular XOR swizzle: byte col ^ ((row&15)<<3). All reads are 2x b64.
__device__ __forceinline__ bf8 lds_frag(const unsigned char* t, int row, int stride, int colb) {
  FR f;
  const unsigned char* base = t + row * stride;
  const int x = (row & 15) << 3;
  f.q[0] = *(const unsigned long long*)(base + (colb ^ x));
  f.q[1] = *(const unsigned long long*)(base + ((colb + 8) ^ x));
  return f.v;
}

__device__ __forceinline__ void lds_w16(unsigned char* t, int row, int stride, int colb, unsigned short v) {
  *(unsigned short*)(t + row * stride + (colb ^ ((row & 15) << 3))) = v;
}

__device__ __forceinline__ void lds_w32(unsigned char* t, int row, int stride, int colb, unsigned int v) {
  *(unsigned int*)(t + row * stride + (colb ^ ((row & 15) << 3))) = v;  // colb 4-aligned
}

__device__ __forceinline__ bf8 gfrag(const float* p) {
  float4 a = *(const float4*)p;
  float4 b = *(const float4*)(p + 4);
  FR f;
  f.u[0] = cvtpk(a.x, a.y);
  f.u[1] = cvtpk(a.z, a.w);
  f.u[2] = cvtpk(b.x, b.y);
  f.u[3] = cvtpk(b.z, b.w);
  return f.v;
}

struct P2 {
  const float* query;
  const float* keys;
  const int* km;
  const float* rpb[3];  // original layout [h][64 q][128 key]
  const unsigned short* wqP[3];
  const unsigned short* wkvP[3];
  const unsigned short* wpP[3];
  const float* bq[3];
  const float* bkv[3];
  const float* bp[3];
  float* out;
};

template <int SD>
__device__ __forceinline__ void do_kv_job(const P2& p, int b, int grow_base, int klocal_base,
                                          int colbase, const unsigned short* wkvP, const float* bkv,
                                          unsigned char* Kst, unsigned char* Vt,
                                          int kdim_base, int vdim_base, int nt0, int nt1, int lane) {
  constexpr int KT = SD / 16;
  const int l31 = lane & 31, hi = lane >> 5;
  bf8 afr[KT];
  const float* ap = p.keys + ((size_t)(grow_base + l31) * B_ + b) * E_ + colbase + hi * 8;
#pragma unroll
  for (int kk = 0; kk < KT; ++kk) afr[kk] = gfrag(ap + kk * 16);
  for (int nt = nt0; nt < nt1; ++nt) {
    f16f acc = ZERO16;
#pragma unroll
    for (int kk = 0; kk < KT; ++kk) {
      bf8 w = *(const bf8*)(wkvP + (((size_t)(nt * KT + kk)) * 64 + lane) * 8);
      acc = __builtin_amdgcn_mfma_f32_32x32x16_bf16(afr[kk], w, acc, 0, 0, 0);
    }
    int n = nt * 32 + l31;
    float bias = bkv[n];
    if (nt * 32 < SD) {  // K half (uniform per nt)
      int col = (kdim_base + n) * 2;
#pragma unroll
      for (int r = 0; r < 16; ++r) {
        int row = klocal_base + (r & 3) + 8 * (r >> 2) + 4 * hi;
        lds_w16(Kst, row, 128, col, f2bf(acc[r] + bias));
      }
    } else {             // V half -> transposed Vt[d][key]; consecutive keys pair
      int d = vdim_base + n - SD;
#pragma unroll
      for (int t2 = 0; t2 < 8; ++t2) {
        int r0 = 2 * t2;
        int key0 = klocal_base + (r0 & 3) + 8 * (r0 >> 2) + 4 * hi;  // even
        lds_w32(Vt, d, 256, key0 * 2, cvtpk(acc[r0] + bias, acc[r0 + 1] + bias));
      }
    }
  }
}

// q-projection with PRE-LOADED A fragments (loads hoisted to phase-1 top)
template <int SD>
__device__ __forceinline__ void do_q_job_pre(const bf8* afr, const P2& p, int qt,
                                             const unsigned short* wqP, const float* bq,
                                             unsigned char* Qst, int qdim_base, int nt0, int nt1,
                                             int lane) {
  constexpr int KT = SD / 16;
  const int l31 = lane & 31, hi = lane >> 5;
  for (int nt = nt0; nt < nt1; ++nt) {
    f16f acc = ZERO16;
#pragma unroll
    for (int kk = 0; kk < KT; ++kk) {
      bf8 w = *(const bf8*)(wqP + (((size_t)(nt * KT + kk)) * 64 + lane) * 8);
      acc = __builtin_amdgcn_mfma_f32_32x32x16_bf16(afr[kk], w, acc, 0, 0, 0);
    }
    int n = nt * 32 + l31;
    float bias = bq[n];
    int col = (qdim_base + n) * 2;
#pragma unroll
    for (int r = 0; r < 16; ++r) {
      int row = qt * 32 + (r & 3) + 8 * (r >> 2) + 4 * hi;
      // fold softmax scale (1/4) and log2e into Q
      lds_w16(Qst, row, 128, col, f2bf((acc[r] + bias) * (0.25f * L2E)));
    }
  }
}

template <int SD>
__device__ __forceinline__ void do_out_job(const P2& p, const unsigned char* Xst, int xdim_base,
                                           int qt, int nt, const unsigned short* wpP, const float* bp,
                                           int b, int colbase, int lane) {
  constexpr int KT = SD / 16;
  const int l31 = lane & 31, hi = lane >> 5;
  f16f acc = ZERO16;
#pragma unroll
  for (int kk = 0; kk < KT; ++kk) {
    bf8 a = lds_frag(Xst, qt * 32 + l31, 128, (xdim_base + kk * 16 + hi * 8) * 2);
    bf8 w = *(const bf8*)(wpP + (((size_t)(nt * KT + kk)) * 64 + lane) * 8);
    acc = __builtin_amdgcn_mfma_f32_32x32x16_bf16(a, w, acc, 0, 0, 0);
  }
  int c = colbase + nt * 32 + l31;
  float bias = bp[nt * 32 + l31];
#pragma unroll
  for (int r = 0; r < 16; ++r) {
    int q = qt * 32 + (r & 3) + 8 * (r >> 2) + 4 * hi;
    p.out[((size_t)q * B_ + b) * E_ + c] = acc[r] + bias;  // 128B-contiguous per 32 lanes
  }
}

// (group,head,qt) attention: FROZEN r7-green dataflow. Swapped QK^T ->
// fixed-shift exp2 -> in-register normalize (f32, before cvt_pk, before
// permlane) -> permlane -> PV -> plain Xst write. r13: psum tree only.
__device__ __forceinline__ void do_attn_job(const P2& p, const unsigned char* Kst,
                                            const unsigned char* Qst, const unsigned char* Vt,
                                            unsigned char* Xst, const float* kmf,
                                            int dimcol, int km_base, const float* rpb_orig,
                                            int qt, int lane) {
  const int l31 = lane & 31, hi = lane >> 5;
  f16f s[4];
#pragma unroll
  for (int kt = 0; kt < 4; ++kt) {
    bf8 kf = lds_frag(Kst, kt * 32 + l31, 128, (dimcol + hi * 8) * 2);
    bf8 qf = lds_frag(Qst, qt * 32 + l31, 128, (dimcol + hi * 8) * 2);
    f16f z = ZERO16;
    s[kt] = __builtin_amdgcn_mfma_f32_32x32x16_bf16(kf, qf, z, 0, 0, 0);  // S^T[key][q]
  }
  // + rpb + mask bias (pre-scaled by log2e; mask carries -8 shift)
  {
    const float* ro = rpb_orig + (qt * 32 + l31) * 128;
#pragma unroll
    for (int kt = 0; kt < 4; ++kt)
#pragma unroll
      for (int r = 0; r < 16; ++r) {
        int krow = kt * 32 + (r & 3) + 8 * (r >> 2) + 4 * hi;
        s[kt][r] = fmaf(ro[krow], L2E, s[kt][r] + kmf[km_base + krow]);
      }
  }
  // fixed-shift softmax: no max pass; 4 per-kt partial sums + tree combine
  float psum[4];
#pragma unroll
  for (int kt = 0; kt < 4; ++kt) {
    float t0 = 0.f;
#pragma unroll
    for (int r = 0; r < 16; ++r) {
      float e = fexp2(s[kt][r]);
      s[kt][r] = e;
      t0 += e;
    }
    psum[kt] = t0;
  }
  float sum = (psum[0] + psum[1]) + (psum[2] + psum[3]);
  sum += __shfl_xor(sum, 32);
  const float inv = 1.0f / sum;

  // pack normalized P to bf16 and redistribute into PV A-frags; PV accumulate
  f16f o = ZERO16;
  const int vrow = dimcol + (l31 & 15);
#pragma unroll
  for (int kt = 0; kt < 4; ++kt) {
    unsigned int pk[8];
#pragma unroll
    for (int j = 0; j < 8; ++j) pk[j] = cvtpk(s[kt][2 * j] * inv, s[kt][2 * j + 1] * inv);
#pragma unroll
    for (int tt = 0; tt < 2; ++tt) {
      FR af;
#if __has_builtin(__builtin_amdgcn_permlane32_swap)
      iv2 w02 = __builtin_amdgcn_permlane32_swap((int)pk[4 * tt], (int)pk[4 * tt + 2], false, false);
      iv2 w13 = __builtin_amdgcn_permlane32_swap((int)pk[4 * tt + 1], (int)pk[4 * tt + 3], false, false);
      af.u[0] = (unsigned)w02[0]; af.u[1] = (unsigned)w13[0];
      af.u[2] = (unsigned)w02[1]; af.u[3] = (unsigned)w13[1];
#else
      unsigned a0 = pk[4 * tt], a1 = pk[4 * tt + 1], b0 = pk[4 * tt + 2], b1 = pk[4 * tt + 3];
      unsigned pa0 = (unsigned)__shfl_xor((int)a0, 32);
      unsigned pa1 = (unsigned)__shfl_xor((int)a1, 32);
      unsigned pb0 = (unsigned)__shfl_xor((int)b0, 32);
      unsigned pb1 = (unsigned)__shfl_xor((int)b1, 32);
      af.u[0] = hi ? pb0 : a0; af.u[1] = hi ? pb1 : a1;
      af.u[2] = hi ? b0 : pa0; af.u[3] = hi ? b1 : pa1;
#endif
      int t = kt * 2 + tt;
      bf8 vf = lds_frag(Vt, vrow, 256, (t * 16 + hi * 8) * 2);
      o = __builtin_amdgcn_mfma_f32_32x32x16_bf16(af.v, vf, o, 0, 0, 0);  // X[q][d]
    }
  }
  if (l31 < 16) {
#pragma unroll
    for (int r = 0; r < 16; ++r) {
      int q = qt * 32 + (r & 3) + 8 * (r >> 2) + 4 * hi;
      lds_w16(Xst, q, 128, (dimcol + l31) * 2, f2bf(o[r]));
    }
  }
}

__launch_bounds__(512, 4)
__global__ void msa13(P2 p) {
  __shared__ __align__(16) unsigned char Qst[8192];    // [64 q][64 dim] bf16
  __shared__ __align__(16) unsigned char Kst[16384];   // [128 key][64 dim] bf16
  __shared__ __align__(16) unsigned char Vt[16384];    // [64 d][128 key] bf16
  __shared__ __align__(16) unsigned char Xst[8192];    // [64 q][64 dim] bf16
  __shared__ float kmf[256];                           // (mask bias - 8) * log2e
  const int bid = blockIdx.x;
  const int b = bid >> 1;
  const int role = bid & 1;
  const int tid = threadIdx.x;
  const int wave = tid >> 6;
  const int lane = tid & 63;
  const int l31 = lane & 31, hi = lane >> 5;

  if (role == 0) {
    // ======== groups 0,1: proj -> attn -> out (3 phases) ========
    if (tid < 256) kmf[tid] = (p.km[(size_t)b * 384 + tid] ? -108.0f : -8.0f) * L2E;
    {
      // hoist q-job A-fragment loads for the double-work waves (wave<4)
      bf8 qaf[2];
      const int qg = wave >> 1, qqt = wave & 1;
      if (wave < 4) {
        const float* qp = p.query + ((size_t)(qqt * 32 + l31) * B_ + b) * E_ + qg * 32 + hi * 8;
#pragma unroll
        for (int kk = 0; kk < 2; ++kk) qaf[kk] = gfrag(qp + kk * 16);
      }
      int g = wave >> 2, mt = wave & 3;
      do_kv_job<32>(p, b, g * 128 + mt * 32, mt * 32, g * 32, p.wkvP[g], p.bkv[g],
                    Kst, Vt, g * 32, g * 32, 0, 2, lane);
      if (wave < 4)
        do_q_job_pre<32>(qaf, p, qqt, p.wqP[qg], p.bq[qg], Qst, qg * 32, 0, 1, lane);
    }
    __syncthreads();
    {
      int g = wave >> 2, head = (wave >> 1) & 1, qt = wave & 1;
      do_attn_job(p, Kst, Qst, Vt, Xst, kmf, g * 32 + head * 16, g * 128,
                  p.rpb[g] + head * 8192, qt, lane);
    }
    __syncthreads();
    if (wave < 4) {
      int g = wave >> 1, qt = wave & 1;
      do_out_job<32>(p, Xst, g * 32, qt, 0, p.wpP[g], p.bp[g], b, g * 32, lane);
    }
  } else {
    // ======== group 2: proj -> attn -> out (3 phases) ========
    if (tid < 128) kmf[tid] = (p.km[(size_t)b * 384 + 256 + tid] ? -108.0f : -8.0f) * L2E;
    {
      bf8 qaf[4];
      const int qqt = wave >> 1, qnt = wave & 1;
      if (wave < 4) {
        const float* qp = p.query + ((size_t)(qqt * 32 + l31) * B_ + b) * E_ + 64 + hi * 8;
#pragma unroll
        for (int kk = 0; kk < 4; ++kk) qaf[kk] = gfrag(qp + kk * 16);
      }
      int mt = wave >> 1, nth = wave & 1;
      do_kv_job<64>(p, b, 256 + mt * 32, mt * 32, 64, p.wkvP[2], p.bkv[2],
                    Kst, Vt, 0, 0, nth * 2, nth * 2 + 2, lane);
      if (wave < 4)
        do_q_job_pre<64>(qaf, p, qqt, p.wqP[2], p.bq[2], Qst, 0, qnt, qnt + 1, lane);
    }
    __syncthreads();
    {
      int head = wave >> 1, qt = wave & 1;
      do_attn_job(p, Kst, Qst, Vt, Xst, kmf, head * 16, 0,
                  p.rpb[2] + head * 8192, qt, lane);
    }
    __syncthreads();
    if (wave < 4) {
      int qt = wave >> 1, nt = wave & 1;
      do_out_job<64>(p, Xst, 0, qt, nt, p.wpP[2], p.bp[2], b, 64, lane);
    }
  }
}

// ---- pre-kernel: pack weights to MFMA B-frag order (bf16) ----
struct PrepP {
  const float* wsrc[9];
  unsigned short* wdst;
};

__global__ void prep(PrepP pp) {
  int i = blockIdx.x * 256 + threadIdx.x;
  if (i < 24576) {
    const int off[10] = {0, 1024, 3072, 4096, 5120, 7168, 8192, 12288, 20480, 24576};
    const int SDs[9] = {32, 32, 32, 32, 32, 32, 64, 64, 64};
    int r = 0;
    while (i >= off[r + 1]) ++r;
    int e = i - off[r];
    int j = e & 7, lane = (e >> 3) & 63, blk = e >> 9;
    int KT = SDs[r] >> 4;
    int nt = blk / KT, kk = blk - nt * KT;
    int row = nt * 32 + (lane & 31);
    int col = kk * 16 + (lane >> 5) * 8 + j;
    pp.wdst[i] = f2bf(pp.wsrc[r][row * SDs[r] + col]);
  }
}

extern "C" void kernel_launch(void* const* d_in, const int* in_sizes, int n_in,
                              void* d_out, int out_size, void* d_ws, size_t ws_size,
                              hipStream_t stream) {
  (void)in_sizes; (void)n_in; (void)out_size; (void)ws_size;
  P2 p;
  PrepP pp;
  p.query = (const float*)d_in[0];
  p.keys = (const float*)d_in[1];
  p.km = (const int*)d_in[2];
  const int base[3] = {3, 10, 17};
  unsigned short* wbf = (unsigned short*)d_ws;
  const int woff[9] = {0, 1024, 3072, 4096, 5120, 7168, 8192, 12288, 20480};
  for (int g = 0; g < 3; ++g) {
    p.rpb[g] = (const float*)d_in[base[g]];
    p.bq[g] = (const float*)d_in[base[g] + 2];
    p.bkv[g] = (const float*)d_in[base[g] + 4];
    p.bp[g] = (const float*)d_in[base[g] + 6];
    p.wqP[g] = wbf + woff[g * 3];
    p.wkvP[g] = wbf + woff[g * 3 + 1];
    p.wpP[g] = wbf + woff[g * 3 + 2];
    pp.wsrc[g * 3] = (const float*)d_in[base[g] + 1];
    pp.wsrc[g * 3 + 1] = (const float*)d_in[base[g] + 3];
    pp.wsrc[g * 3 + 2] = (const float*)d_in[base[g] + 5];
  }
  p.out = (float*)d_out;
  pp.wdst = wbf;

  prep<<<96, 256, 0, stream>>>(pp);
  msa13<<<4096, 512, 0, stream>>>(p);
}